// Round 8
// baseline (1468.282 us; speedup 1.0000x reference)
//
#include <hip/hip_runtime.h>

typedef float f32x4 __attribute__((ext_vector_type(4)));
typedef unsigned int u32x4 __attribute__((ext_vector_type(4)));
typedef _Float16 f16x8 __attribute__((ext_vector_type(8)));
typedef unsigned short u16;
typedef unsigned int u32;

// ---- constants ----
#define NWIN 8192
#define MAX_LOG_SCALE 4.605170185988091f  // log(100)
#define LOG2E 1.4426950408889634f

// Barrier-free design: wave wv owns head wv end-to-end. x1/x2 fragments come
// straight from global (f32 -> f16 in flight); all layout bounces use a
// wave-private LDS slice (in-order DS pipe, no barriers). The ONLY cross-wave
// dataflow is the final projection (k-sum over all 128 channels), so exactly
// one __syncthreads() survives (O complete -> proj reads O).
// LDS: O [64][128] f16 swizzled (16 KB) + 4 KB bounce per wave = 32 KB.
//   bounce +0    (2 KB): vT [32][64] f16 stride128 (pass V) -> P [16][64] (pass Q)
//   bounce +2048 (1.25KB): k/q C->frag bounce [16][32] f16, stride 80 (padded)
#define RO 0
#define RBNC 16384
#define LDS_BYTES 32768

__device__ __forceinline__ void mfma16(f32x4& acc, u32x4 a, u32x4 b) {
  acc = __builtin_amdgcn_mfma_f32_16x16x32_f16(
      __builtin_bit_cast(f16x8, a), __builtin_bit_cast(f16x8, b), acc, 0, 0, 0);
}

__device__ __forceinline__ u16 f2h(float f) {
  return __builtin_bit_cast(u16, (_Float16)f);
}
__device__ __forceinline__ u32 pkh(float x, float y) {  // packed f32->f16 (RTZ)
  return __builtin_bit_cast(u32, __builtin_amdgcn_cvt_pkrtz(x, y));
}

// XOR swizzle within a row (row stride 256B or 128B); bijective, stays in-row.
__device__ __forceinline__ int swz(int row, int colbyte) {
  return colbyte ^ ((row & 7) << 4);
}
__device__ __forceinline__ u32x4 ldsfrag(const char* p, int row, int colbyte, int stride) {
  return *(const u32x4*)(p + row * stride + swz(row, colbyte));
}
__device__ __forceinline__ void lds_st16(char* p, int row, int colbyte, int stride, u16 v) {
  *(u16*)(p + row * stride + swz(row, colbyte)) = v;
}
// small bounce [16][32] f16: padded stride 80B (banks spread, no swizzle needed)
__device__ __forceinline__ u32x4 bnc32_ld(const char* p, int row, int colbyte) {
  return *(const u32x4*)(p + row * 80 + colbyte);
}
__device__ __forceinline__ void bnc32_st(char* p, int row, int colbyte, u16 v) {
  *(u16*)(p + row * 80 + colbyte) = v;
}
// f16 weight frag from global (8 consecutive cols of row-major [*][128])
__device__ __forceinline__ u32x4 gfrag(const u16* p) {
  return *(const u32x4*)p;
}
// f32 activation frag from global, converted to f16 in flight
__device__ __forceinline__ u32x4 gfrag32(const float* p) {
  float4 lo = *(const float4*)p;
  float4 hi = *(const float4*)(p + 4);
  u32x4 r = { pkh(lo.x, lo.y), pkh(lo.z, lo.w), pkh(hi.x, hi.y), pkh(hi.z, hi.w) };
  return r;
}

// ---------- weight prep: f32 -> f16 (contiguous qw|kvw|pw) + head scales ----------
__global__ void wca_prep(const float* __restrict__ qw, const float* __restrict__ kvw,
                         const float* __restrict__ pw, const float* __restrict__ ls,
                         u16* __restrict__ wh, float* __restrict__ scales) {
  int t = blockIdx.x * 256 + threadIdx.x;   // 0..16383, one float4 each
  int e = t * 4;
  const float* src;
  int off;
  if (e < 16384)      { src = qw;  off = e; }
  else if (e < 49152) { src = kvw; off = e - 16384; }
  else                { src = pw;  off = e - 49152; }
  float4 v = *(const float4*)(src + off);
  uint2 o = { pkh(v.x, v.y), pkh(v.z, v.w) };
  *(uint2*)(wh + e) = o;
  // pre-fold log2(e) so softmax uses exp2 (single v_exp_f32)
  if (t < 4) scales[t] = __expf(fminf(ls[t], MAX_LOG_SCALE)) * LOG2E;
}

// ---------- main kernel: one window per block, wave = head, 1 barrier ----------
__global__ void __launch_bounds__(256, 4) wca_kernel(
    const float* __restrict__ x1, const float* __restrict__ x2,
    const float* __restrict__ qb, const float* __restrict__ vb,
    const float* __restrict__ pb, const u16* __restrict__ wh,
    const float* __restrict__ scales, float* __restrict__ out) {
  __shared__ char smem[LDS_BYTES];
  const int b = blockIdx.x;
  const int tid = threadIdx.x;
  const int wv = tid >> 6;          // wave = head 0..3
  const int lane = tid & 63;
  const int lr = lane & 15;
  const int lg = lane >> 4;
  const int h32 = wv * 32;
  const float* x1w = x1 + (size_t)b * 8192;
  const float* x2w = x2 + (size_t)b * 8192;
  const u16* qw_  = wh;                    // 128x128
  const u16* kvwk = wh + 16384;            // k-part rows 0..127
  const u16* kvwv = wh + 16384 + 128 * 128; // v-part rows 0..127
  const u16* pw_  = wh + 49152;            // 128x128
  char* bnc  = smem + RBNC + wv * 4096;    // wave-private
  char* bncS = bnc + 2048;

  // ---- pass V: vT(c,m) = sum_k kvw_v[h32+c][k] * x2[m][k] + vb ----
  u32x4 bv[2][2];
  {
    u32x4 akv[2][4];
#pragma unroll
    for (int jt = 0; jt < 2; ++jt)
#pragma unroll
      for (int kc = 0; kc < 4; ++kc)
        akv[jt][kc] = gfrag(kvwv + (h32 + jt * 16 + lr) * 128 + kc * 32 + lg * 8);
    f32x4 vc[2][4];
#pragma unroll
    for (int jt = 0; jt < 2; ++jt)
#pragma unroll
      for (int nt = 0; nt < 4; ++nt) vc[jt][nt] = (f32x4){0.f, 0.f, 0.f, 0.f};
#pragma unroll
    for (int nt = 0; nt < 4; ++nt) {
      u32x4 bx[4];
#pragma unroll
      for (int kc = 0; kc < 4; ++kc)
        bx[kc] = gfrag32(x2w + (nt * 16 + lr) * 128 + kc * 32 + lg * 8);
#pragma unroll
      for (int jt = 0; jt < 2; ++jt)
#pragma unroll
        for (int kc = 0; kc < 4; ++kc) mfma16(vc[jt][nt], akv[jt][kc], bx[kc]);
    }
    // bias + bounce vT [c:32][m:64] (stride 128, swizzled), then read bv frags
#pragma unroll
    for (int jt = 0; jt < 2; ++jt) {
      float vbias[4];
#pragma unroll
      for (int i = 0; i < 4; ++i) vbias[i] = vb[h32 + jt * 16 + lg * 4 + i];
#pragma unroll
      for (int nt = 0; nt < 4; ++nt)
#pragma unroll
        for (int i = 0; i < 4; ++i)
          lds_st16(bnc, jt * 16 + lg * 4 + i, (nt * 16 + lr) * 2, 128,
                   f2h(vc[jt][nt][i] + vbias[i]));
    }
#pragma unroll
    for (int ct = 0; ct < 2; ++ct)
#pragma unroll
      for (int kc = 0; kc < 2; ++kc)
        bv[ct][kc] = ldsfrag(bnc, ct * 16 + lr, kc * 64 + lg * 16, 128);
  }

  // ---- pass K: k rows m (L2-normalized over head cols) -> bk[mt] frags ----
  u32x4 bk[4];
  {
    u32x4 bkw[2][4];
#pragma unroll
    for (int jt = 0; jt < 2; ++jt)
#pragma unroll
      for (int kc = 0; kc < 4; ++kc)
        bkw[jt][kc] = gfrag(kvwk + (h32 + jt * 16 + lr) * 128 + kc * 32 + lg * 8);
#pragma unroll
    for (int mt = 0; mt < 4; ++mt) {
      f32x4 c0 = {0.f, 0.f, 0.f, 0.f}, c1 = {0.f, 0.f, 0.f, 0.f};
#pragma unroll
      for (int kc = 0; kc < 4; ++kc) {
        u32x4 ax = gfrag32(x2w + (mt * 16 + lr) * 128 + kc * 32 + lg * 8);
        mfma16(c0, ax, bkw[0][kc]);
        mfma16(c1, ax, bkw[1][kc]);
      }
      float s[4];
#pragma unroll
      for (int i = 0; i < 4; ++i) s[i] = c0[i] * c0[i] + c1[i] * c1[i];
#pragma unroll
      for (int m = 1; m < 16; m <<= 1)
#pragma unroll
        for (int i = 0; i < 4; ++i) s[i] += __shfl_xor(s[i], m, 64);
#pragma unroll
      for (int i = 0; i < 4; ++i) {
        float rn = 1.0f / fmaxf(sqrtf(s[i]), 1e-12f);
        bnc32_st(bncS, lg * 4 + i, lr * 2, f2h(c0[i] * rn));
        bnc32_st(bncS, lg * 4 + i, (16 + lr) * 2, f2h(c1[i] * rn));
      }
      bk[mt] = bnc32_ld(bncS, lr, lg * 16);  // wave-local RAW
    }
  }

  // ---- pass Q fused with QK^T -> softmax -> PV per row-block nt ----
  const float sc = scales[wv];  // includes log2(e)
  const float qb0 = qb[h32 + lr], qb1 = qb[h32 + 16 + lr];
#pragma unroll
  for (int nt = 0; nt < 4; ++nt) {
    f32x4 q0 = {0.f, 0.f, 0.f, 0.f}, q1 = {0.f, 0.f, 0.f, 0.f};
#pragma unroll
    for (int kc = 0; kc < 4; ++kc) {   // qw streamed (L2) to bound registers
      u32x4 a = gfrag32(x1w + (nt * 16 + lr) * 128 + kc * 32 + lg * 8);
      u32x4 w0 = gfrag(qw_ + (h32 + lr) * 128 + kc * 32 + lg * 8);
      u32x4 w1 = gfrag(qw_ + (h32 + 16 + lr) * 128 + kc * 32 + lg * 8);
      mfma16(q0, a, w0);
      mfma16(q1, a, w1);
    }
    float s[4];
#pragma unroll
    for (int i = 0; i < 4; ++i) {
      q0[i] += qb0; q1[i] += qb1;
      s[i] = q0[i] * q0[i] + q1[i] * q1[i];
    }
#pragma unroll
    for (int m = 1; m < 16; m <<= 1)
#pragma unroll
      for (int i = 0; i < 4; ++i) s[i] += __shfl_xor(s[i], m, 64);
#pragma unroll
    for (int i = 0; i < 4; ++i) {
      float rn = 1.0f / fmaxf(sqrtf(s[i]), 1e-12f);
      bnc32_st(bncS, lg * 4 + i, lr * 2, f2h(q0[i] * rn));
      bnc32_st(bncS, lg * 4 + i, (16 + lr) * 2, f2h(q1[i] * rn));
    }
    u32x4 aq = bnc32_ld(bncS, lr, lg * 16);  // wave-local RAW

    f32x4 att[4];
#pragma unroll
    for (int mt = 0; mt < 4; ++mt) {
      f32x4 z = {0.f, 0.f, 0.f, 0.f};
      mfma16(z, aq, bk[mt]);
      att[mt] = z;
    }
    // softmax; logits*log2e <= sc -> fixed max bound sc (no max reduce)
    float sum[4] = {0.f, 0.f, 0.f, 0.f};
#pragma unroll
    for (int i = 0; i < 4; ++i)
#pragma unroll
      for (int mt = 0; mt < 4; ++mt) {
        float p = exp2f(fmaf(att[mt][i], sc, -sc));
        att[mt][i] = p;
        sum[i] += p;
      }
#pragma unroll
    for (int m = 1; m < 16; m <<= 1)
#pragma unroll
      for (int i = 0; i < 4; ++i) sum[i] += __shfl_xor(sum[i], m, 64);
#pragma unroll
    for (int i = 0; i < 4; ++i) {
      float rs = 1.0f / sum[i];
#pragma unroll
      for (int mt = 0; mt < 4; ++mt)
        lds_st16(bnc, lg * 4 + i, (mt * 16 + lr) * 2, 128, f2h(att[mt][i] * rs));
    }
    u32x4 ap[2];
#pragma unroll
    for (int kc = 0; kc < 2; ++kc)
      ap[kc] = ldsfrag(bnc, lr, kc * 64 + lg * 16, 128);  // wave-local RAW
#pragma unroll
    for (int ct = 0; ct < 2; ++ct) {
      f32x4 z = {0.f, 0.f, 0.f, 0.f};
#pragma unroll
      for (int kc = 0; kc < 2; ++kc) mfma16(z, ap[kc], bv[ct][kc]);
      // O-tile store: rows nt*16+lg*4+i, cols h32 + ct*16 + lr
#pragma unroll
      for (int i = 0; i < 4; ++i)
        lds_st16(smem + RO, nt * 16 + lg * 4 + i, (h32 + ct * 16 + lr) * 2, 256,
                 f2h(z[i]));
    }
  }

  // hoist proj weight frags (L2) to overlap with the barrier
  u32x4 bp[2][4];
#pragma unroll
  for (int ct = 0; ct < 2; ++ct)
#pragma unroll
    for (int kc = 0; kc < 4; ++kc)
      bp[ct][kc] = gfrag(pw_ + (h32 + ct * 16 + lr) * 128 + kc * 32 + lg * 8);
  float pbv[2] = { pb[h32 + lr], pb[h32 + 16 + lr] };

  __syncthreads();  // (1) the only barrier: O complete

  // ---- proj (column-scheme): out[:, h32..h32+32) = O @ pw[own rows]^T + pb ----
  {
    float* ob = out + (size_t)b * 8192;
#pragma unroll
    for (int np = 0; np < 2; ++np) {
      u32x4 af[2][4];
#pragma unroll
      for (int t = 0; t < 2; ++t)
#pragma unroll
        for (int kc = 0; kc < 4; ++kc)
          af[t][kc] = ldsfrag(smem + RO, (np * 2 + t) * 16 + lr, kc * 64 + lg * 16, 256);
#pragma unroll
      for (int t = 0; t < 2; ++t)
#pragma unroll
        for (int ct = 0; ct < 2; ++ct) {
          f32x4 acc = {0.f, 0.f, 0.f, 0.f};
#pragma unroll
          for (int kc = 0; kc < 4; ++kc) mfma16(acc, af[t][kc], bp[ct][kc]);
#pragma unroll
          for (int i = 0; i < 4; ++i) {
            int row = (np * 2 + t) * 16 + lg * 4 + i;
            ob[row * 128 + h32 + ct * 16 + lr] = acc[i] + pbv[ct];
          }
        }
    }
  }
}

extern "C" void kernel_launch(void* const* d_in, const int* in_sizes, int n_in,
                              void* d_out, int out_size, void* d_ws, size_t ws_size,
                              hipStream_t stream) {
  const float* x1 = (const float*)d_in[0];
  const float* x2 = (const float*)d_in[1];
  const float* qw = (const float*)d_in[2];
  const float* qb = (const float*)d_in[3];
  const float* kvw = (const float*)d_in[4];
  const float* vb = (const float*)d_in[5];
  const float* ls = (const float*)d_in[6];
  const float* pw = (const float*)d_in[7];
  const float* pb = (const float*)d_in[8];
  u16* wh = (u16*)d_ws;                           // 65536 f16 = 128 KB
  float* scales = (float*)((char*)d_ws + 131072); // 4 floats

  wca_prep<<<64, 256, 0, stream>>>(qw, kvw, pw, ls, wh, scales);
  wca_kernel<<<NWIN, 256, 0, stream>>>(x1, x2, qb, vb, pb, wh, scales, (float*)d_out);
}

// Round 9
// 410.044 us; speedup vs baseline: 3.5808x; 3.5808x over previous
//
#include <hip/hip_runtime.h>

typedef float f32x4 __attribute__((ext_vector_type(4)));
typedef unsigned int u32x4 __attribute__((ext_vector_type(4)));
typedef _Float16 f16x8 __attribute__((ext_vector_type(8)));
typedef unsigned short u16;
typedef unsigned int u32;

// ---- constants ----
#define NWIN 8192
#define MAX_LOG_SCALE 4.605170185988091f  // log(100)
#define LOG2E 1.4426950408889634f

// Wave = head end-to-end; 3 barriers total.
// LDS (24 KB -> 6 blocks/CU by LDS; occupancy set by VGPR (~5 blocks)):
//   RX2  [0,16K):  x2 f16 [64][128] swz (read by all waves in V+K passes)
//                  -> O [64][128] swz after barrier (2)
//   RBNC [16K,24K): per-wave 2 KB bounce slice, sequentially reused:
//                  vT chunk [16][64] s128 -> k strip [16][32] s80 ->
//                  q strip [16][32] s80 -> P [16][64] s128  (all wave-local)
// x1 is read DIRECT from global exactly once per wave (4x per block, loosely
// synchronized -> L2-served; x2 would be read 8x -> must be LDS-staged;
// round 8 proved direct-global x re-reads thrash per-XCD L2 (1.4 GB fetch)).
#define RX2 0
#define RBNC 16384
#define LDS_BYTES 24576

__device__ __forceinline__ void mfma16(f32x4& acc, u32x4 a, u32x4 b) {
  acc = __builtin_amdgcn_mfma_f32_16x16x32_f16(
      __builtin_bit_cast(f16x8, a), __builtin_bit_cast(f16x8, b), acc, 0, 0, 0);
}

__device__ __forceinline__ u16 f2h(float f) {
  return __builtin_bit_cast(u16, (_Float16)f);
}
__device__ __forceinline__ u32 pkh(float x, float y) {  // packed f32->f16 (RTZ)
  return __builtin_bit_cast(u32, __builtin_amdgcn_cvt_pkrtz(x, y));
}

// XOR swizzle within a row (row stride 256B or 128B); bijective, stays in-row.
__device__ __forceinline__ int swz(int row, int colbyte) {
  return colbyte ^ ((row & 7) << 4);
}
__device__ __forceinline__ u32x4 ldsfrag(const char* p, int row, int colbyte, int stride) {
  return *(const u32x4*)(p + row * stride + swz(row, colbyte));
}
__device__ __forceinline__ void lds_st16(char* p, int row, int colbyte, int stride, u16 v) {
  *(u16*)(p + row * stride + swz(row, colbyte)) = v;
}
// small bounce [16][32] f16: padded stride 80B (banks spread, no swizzle)
__device__ __forceinline__ u32x4 bnc32_ld(const char* p, int row, int colbyte) {
  return *(const u32x4*)(p + row * 80 + colbyte);
}
__device__ __forceinline__ void bnc32_st(char* p, int row, int colbyte, u16 v) {
  *(u16*)(p + row * 80 + colbyte) = v;
}
__device__ __forceinline__ u32x4 gfrag(const u16* p) {
  return *(const u32x4*)p;
}
// f32 activation frag from global, converted to f16 in flight (32B/lane,
// wave covers 16 rows x 128B contiguous -> full-line coalescing)
__device__ __forceinline__ u32x4 gfrag32(const float* p) {
  float4 lo = *(const float4*)p;
  float4 hi = *(const float4*)(p + 4);
  u32x4 r = { pkh(lo.x, lo.y), pkh(lo.z, lo.w), pkh(hi.x, hi.y), pkh(hi.z, hi.w) };
  return r;
}

// ---------- weight prep: f32 -> f16 (contiguous qw|kvw|pw) + head scales ----------
__global__ void wca_prep(const float* __restrict__ qw, const float* __restrict__ kvw,
                         const float* __restrict__ pw, const float* __restrict__ ls,
                         u16* __restrict__ wh, float* __restrict__ scales) {
  int t = blockIdx.x * 256 + threadIdx.x;   // 0..16383, one float4 each
  int e = t * 4;
  const float* src;
  int off;
  if (e < 16384)      { src = qw;  off = e; }
  else if (e < 49152) { src = kvw; off = e - 16384; }
  else                { src = pw;  off = e - 49152; }
  float4 v = *(const float4*)(src + off);
  uint2 o = { pkh(v.x, v.y), pkh(v.z, v.w) };
  *(uint2*)(wh + e) = o;
  if (t < 4) scales[t] = __expf(fminf(ls[t], MAX_LOG_SCALE)) * LOG2E;
}

// ---------- main kernel: one window per block, wave = head, 3 barriers ----------
__global__ void __launch_bounds__(256, 4) wca_kernel(
    const float* __restrict__ x1, const float* __restrict__ x2,
    const float* __restrict__ qb, const float* __restrict__ vb,
    const float* __restrict__ pb, const u16* __restrict__ wh,
    const float* __restrict__ scales, float* __restrict__ out) {
  __shared__ char smem[LDS_BYTES];
  const int b = blockIdx.x;
  const int tid = threadIdx.x;
  const int wv = tid >> 6;          // wave = head 0..3
  const int lane = tid & 63;
  const int lr = lane & 15;
  const int lg = lane >> 4;
  const int h32 = wv * 32;
  const float* x1w = x1 + (size_t)b * 8192;
  const float* x2w = x2 + (size_t)b * 8192;
  const u16* qw_  = wh;                     // 128x128
  const u16* kvwk = wh + 16384;             // k-part rows 0..127
  const u16* kvwv = wh + 16384 + 16384;     // v-part rows 0..127
  const u16* pw_  = wh + 49152;             // 128x128
  char* bnc = smem + RBNC + wv * 2048;      // wave-private bounce slice

  // ---- phase 0: stage x2 -> f16 LDS (8 loads/thread hoisted) ----
  {
    const float4* p2 = (const float4*)x2w;
    float4 c[8];
#pragma unroll
    for (int i = 0; i < 8; ++i) c[i] = p2[i * 256 + tid];
#pragma unroll
    for (int i = 0; i < 8; ++i) {
      int e = (i * 256 + tid) * 4;
      int row = e >> 7;
      int colb = (e & 127) * 2;
      uint2 pc = { pkh(c[i].x, c[i].y), pkh(c[i].z, c[i].w) };
      *(uint2*)(smem + RX2 + row * 256 + swz(row, colb)) = pc;
    }
  }
  __syncthreads();  // (1) x2 visible

  // ---- V pass: vT(c,m) = sum_k kvw_v[h32+c][k]*x2[m][k] + vb, c in own head ----
  u32x4 bv[2][2];
  {
    u32x4 akv[2][4];
#pragma unroll
    for (int jt = 0; jt < 2; ++jt)
#pragma unroll
      for (int kc = 0; kc < 4; ++kc)
        akv[jt][kc] = gfrag(kvwv + (h32 + jt * 16 + lr) * 128 + kc * 32 + lg * 8);
#pragma unroll
    for (int jt = 0; jt < 2; ++jt) {
      f32x4 vc[4];
#pragma unroll
      for (int nt = 0; nt < 4; ++nt) vc[nt] = (f32x4){0.f, 0.f, 0.f, 0.f};
#pragma unroll
      for (int nt = 0; nt < 4; ++nt) {
        u32x4 bx[4];
#pragma unroll
        for (int kc = 0; kc < 4; ++kc)
          bx[kc] = ldsfrag(smem + RX2, nt * 16 + lr, kc * 64 + lg * 16, 256);
#pragma unroll
        for (int kc = 0; kc < 4; ++kc) mfma16(vc[nt], akv[jt][kc], bx[kc]);
      }
      float vbias[4];
#pragma unroll
      for (int i = 0; i < 4; ++i) vbias[i] = vb[h32 + jt * 16 + lg * 4 + i];
      // bounce vT chunk [c_local:16][m:64] stride 128 swz (wave-local)
#pragma unroll
      for (int nt = 0; nt < 4; ++nt)
#pragma unroll
        for (int i = 0; i < 4; ++i)
          lds_st16(bnc, lg * 4 + i, (nt * 16 + lr) * 2, 128, f2h(vc[nt][i] + vbias[i]));
#pragma unroll
      for (int kc = 0; kc < 2; ++kc)
        bv[jt][kc] = ldsfrag(bnc, lr, kc * 64 + lg * 16, 128);  // wave-local RAW
    }
  }

  // ---- K pass: k rows m, L2-normalized over own head cols -> bk[mt] ----
  u32x4 bk[4];
  {
    u32x4 bkw[2][4];
#pragma unroll
    for (int jt = 0; jt < 2; ++jt)
#pragma unroll
      for (int kc = 0; kc < 4; ++kc)
        bkw[jt][kc] = gfrag(kvwk + (h32 + jt * 16 + lr) * 128 + kc * 32 + lg * 8);
#pragma unroll
    for (int mt = 0; mt < 4; ++mt) {
      f32x4 c0 = {0.f, 0.f, 0.f, 0.f}, c1 = {0.f, 0.f, 0.f, 0.f};
#pragma unroll
      for (int kc = 0; kc < 4; ++kc) {
        u32x4 ax = ldsfrag(smem + RX2, mt * 16 + lr, kc * 64 + lg * 16, 256);
        mfma16(c0, ax, bkw[0][kc]);
        mfma16(c1, ax, bkw[1][kc]);
      }
      float s[4];
#pragma unroll
      for (int i = 0; i < 4; ++i) s[i] = c0[i] * c0[i] + c1[i] * c1[i];
#pragma unroll
      for (int m = 1; m < 16; m <<= 1)
#pragma unroll
        for (int i = 0; i < 4; ++i) s[i] += __shfl_xor(s[i], m, 64);
#pragma unroll
      for (int i = 0; i < 4; ++i) {
        float rn = 1.0f / fmaxf(sqrtf(s[i]), 1e-12f);
        bnc32_st(bnc, lg * 4 + i, lr * 2, f2h(c0[i] * rn));
        bnc32_st(bnc, lg * 4 + i, (16 + lr) * 2, f2h(c1[i] * rn));
      }
      bk[mt] = bnc32_ld(bnc, lr, lg * 16);  // wave-local RAW
    }
  }
  __syncthreads();  // (2) all waves done reading x2 -> O may overlay RX2

  // ---- Q + attention per nt: x1 direct from global (single read per wave) ----
  const float sc = scales[wv];  // includes log2(e)
  const float qb0 = qb[h32 + lr], qb1 = qb[h32 + 16 + lr];
#pragma unroll
  for (int nt = 0; nt < 4; ++nt) {
    f32x4 q0 = {0.f, 0.f, 0.f, 0.f}, q1 = {0.f, 0.f, 0.f, 0.f};
#pragma unroll
    for (int kc = 0; kc < 4; ++kc) {
      u32x4 a = gfrag32(x1w + (nt * 16 + lr) * 128 + kc * 32 + lg * 8);
      u32x4 w0 = gfrag(qw_ + (h32 + lr) * 128 + kc * 32 + lg * 8);
      u32x4 w1 = gfrag(qw_ + (h32 + 16 + lr) * 128 + kc * 32 + lg * 8);
      mfma16(q0, a, w0);
      mfma16(q1, a, w1);
    }
    float s[4];
#pragma unroll
    for (int i = 0; i < 4; ++i) {
      q0[i] += qb0; q1[i] += qb1;
      s[i] = q0[i] * q0[i] + q1[i] * q1[i];
    }
#pragma unroll
    for (int m = 1; m < 16; m <<= 1)
#pragma unroll
      for (int i = 0; i < 4; ++i) s[i] += __shfl_xor(s[i], m, 64);
#pragma unroll
    for (int i = 0; i < 4; ++i) {
      float rn = 1.0f / fmaxf(sqrtf(s[i]), 1e-12f);
      bnc32_st(bnc, lg * 4 + i, lr * 2, f2h(q0[i] * rn));
      bnc32_st(bnc, lg * 4 + i, (16 + lr) * 2, f2h(q1[i] * rn));
    }
    u32x4 aq = bnc32_ld(bnc, lr, lg * 16);  // wave-local RAW

    f32x4 att[4];
#pragma unroll
    for (int mt = 0; mt < 4; ++mt) {
      f32x4 z = {0.f, 0.f, 0.f, 0.f};
      mfma16(z, aq, bk[mt]);
      att[mt] = z;
    }
    // softmax; logits*log2e <= sc -> fixed max bound sc (no max reduce)
    float sum[4] = {0.f, 0.f, 0.f, 0.f};
#pragma unroll
    for (int i = 0; i < 4; ++i)
#pragma unroll
      for (int mt = 0; mt < 4; ++mt) {
        float p = exp2f(fmaf(att[mt][i], sc, -sc));
        att[mt][i] = p;
        sum[i] += p;
      }
#pragma unroll
    for (int m = 1; m < 16; m <<= 1)
#pragma unroll
      for (int i = 0; i < 4; ++i) sum[i] += __shfl_xor(sum[i], m, 64);
    // P strip [n_local:16][m:64] stride 128 swz (overwrites q-strip; both dead after)
#pragma unroll
    for (int i = 0; i < 4; ++i) {
      float rs = 1.0f / sum[i];
#pragma unroll
      for (int mt = 0; mt < 4; ++mt)
        lds_st16(bnc, lg * 4 + i, (mt * 16 + lr) * 2, 128, f2h(att[mt][i] * rs));
    }
    u32x4 ap[2];
#pragma unroll
    for (int kc = 0; kc < 2; ++kc)
      ap[kc] = ldsfrag(bnc, lr, kc * 64 + lg * 16, 128);  // wave-local RAW
#pragma unroll
    for (int ct = 0; ct < 2; ++ct) {
      f32x4 z = {0.f, 0.f, 0.f, 0.f};
#pragma unroll
      for (int kc = 0; kc < 2; ++kc) mfma16(z, ap[kc], bv[ct][kc]);
      // O into RX2 overlay: rows nt*16+lg*4+i, cols h32+ct*16+lr (own head only)
#pragma unroll
      for (int i = 0; i < 4; ++i)
        lds_st16(smem + RX2, nt * 16 + lg * 4 + i, (h32 + ct * 16 + lr) * 2, 256,
                 f2h(z[i]));
    }
  }

  // hoist proj weight frags (L2) to overlap with the barrier
  u32x4 bp[2][4];
#pragma unroll
  for (int ct = 0; ct < 2; ++ct)
#pragma unroll
    for (int kc = 0; kc < 4; ++kc)
      bp[ct][kc] = gfrag(pw_ + (h32 + ct * 16 + lr) * 128 + kc * 32 + lg * 8);
  float pbv[2] = { pb[h32 + lr], pb[h32 + 16 + lr] };

  __syncthreads();  // (3) O complete

  // ---- proj (column-scheme): out[:, h32..h32+32) = O @ pw[own rows]^T + pb ----
  {
    float* ob = out + (size_t)b * 8192;
#pragma unroll
    for (int np = 0; np < 2; ++np) {
      u32x4 af[2][4];
#pragma unroll
      for (int t = 0; t < 2; ++t)
#pragma unroll
        for (int kc = 0; kc < 4; ++kc)
          af[t][kc] = ldsfrag(smem + RX2, (np * 2 + t) * 16 + lr, kc * 64 + lg * 16, 256);
#pragma unroll
      for (int t = 0; t < 2; ++t)
#pragma unroll
        for (int ct = 0; ct < 2; ++ct) {
          f32x4 acc = {0.f, 0.f, 0.f, 0.f};
#pragma unroll
          for (int kc = 0; kc < 4; ++kc) mfma16(acc, af[t][kc], bp[ct][kc]);
#pragma unroll
          for (int i = 0; i < 4; ++i) {
            int row = (np * 2 + t) * 16 + lg * 4 + i;
            ob[row * 128 + h32 + ct * 16 + lr] = acc[i] + pbv[ct];
          }
        }
    }
  }
}

extern "C" void kernel_launch(void* const* d_in, const int* in_sizes, int n_in,
                              void* d_out, int out_size, void* d_ws, size_t ws_size,
                              hipStream_t stream) {
  const float* x1 = (const float*)d_in[0];
  const float* x2 = (const float*)d_in[1];
  const float* qw = (const float*)d_in[2];
  const float* qb = (const float*)d_in[3];
  const float* kvw = (const float*)d_in[4];
  const float* vb = (const float*)d_in[5];
  const float* ls = (const float*)d_in[6];
  const float* pw = (const float*)d_in[7];
  const float* pb = (const float*)d_in[8];
  u16* wh = (u16*)d_ws;                           // 65536 f16 = 128 KB
  float* scales = (float*)((char*)d_ws + 131072); // 4 floats

  wca_prep<<<64, 256, 0, stream>>>(qw, kvw, pw, ls, wh, scales);
  wca_kernel<<<NWIN, 256, 0, stream>>>(x1, x2, qb, vb, pb, wh, scales, (float*)d_out);
}